// Round 8
// baseline (122.803 us; speedup 1.0000x reference)
//
#include <hip/hip_runtime.h>

// y: [B=8, C=192, H=64, W=64] f32; codebooks: [G=8, K=512, d=24] f32
// out (f32, concat): universal_ctx | y_ba | code_index [B,1,G,H,W]
#define B_   8
#define C_   192
#define HW_  4096
#define G_   8
#define K_   512
#define D_   24
#define CBSZ (K_ * D_)
#define THREADS 256
#define TILES_PER_BLOCK 8     // 128 positions per block

typedef float  f32x4 __attribute__((ext_vector_type(4)));
typedef short  s16x8 __attribute__((ext_vector_type(8)));
typedef short  s16x4 __attribute__((ext_vector_type(4)));
typedef unsigned long long u64;

static __device__ __forceinline__ unsigned umin_(unsigned a, unsigned b){return a<b?a:b;}
static __device__ __forceinline__ unsigned umax_(unsigned a, unsigned b){return a>b?a:b;}
static __device__ __forceinline__ unsigned short f2bf(float x){       // RNE f32->bf16
    unsigned u=__float_as_uint(x);
    return (unsigned short)((u + 0x7FFFu + ((u>>16)&1u))>>16);
}
static __device__ __forceinline__ float bf2f(unsigned short h){return __uint_as_float(((unsigned)h)<<16);}

__global__ __launch_bounds__(THREADS, 5) void vq_mfma3(
    const float* __restrict__ y, const float* __restrict__ cb, float* __restrict__ out)
{
    // [tile:32][lane:64][j:8] bf16; lanes 0..47 = e_hi (k<24), lanes 48..63 j=0,1 =
    // e2_hi/e2_lo (k=24,25; A holds 1.0 there), rest zero. 32 KiB -> 5 blocks/CU.
    __shared__ unsigned short sB[32 * 512];

    const int bid = blockIdx.x;
    const int g = bid & 7;
    const int chunk = bid >> 3;
    const int tid = threadIdx.x;
    const int wave = tid >> 6, lane = tid & 63;
    const int c = lane & 15, q = lane >> 4;

    const float* cbg = cb + g * CBSZ;     // 32-bit offset ok

    // ---- stage codebook hi-bf16 fragments (float4 loads, b64 LDS writes) ----
    {
        const f32x4* cb4 = (const f32x4*)cbg;
        for (int i = tid; i < CBSZ/4; i += THREADS) {
            f32x4 v = cb4[i];
            int i4 = i << 2;
            int n  = i4 / 24;          // float4 never crosses a row (24%4==0)
            int k0 = i4 - n * 24;
            int off = (n >> 4) * 512 + (((k0 >> 3) << 4) + (n & 15)) * 8 + (k0 & 7);
            s16x4 h;
            h[0]=(short)f2bf(v[0]); h[1]=(short)f2bf(v[1]);
            h[2]=(short)f2bf(v[2]); h[3]=(short)f2bf(v[3]);
            *(s16x4*)(&sB[off]) = h;
        }
        for (int n = tid; n < K_; n += THREADS) {
            const float* row = cbg + n * D_;
            double s0 = 0.0, s1 = 0.0;
            #pragma unroll
            for (int j = 0; j < D_; j += 2) {
                double v0 = (double)row[j], v1 = (double)row[j+1];
                s0 = fma(v0,v0,s0); s1 = fma(v1,v1,s1);
            }
            double s = s0 + s1;
            unsigned short ehi = f2bf((float)s);
            unsigned short elo = f2bf((float)(s - (double)bf2f(ehi)));
            unsigned* dst = (unsigned*)(&sB[(n >> 4) * 512 + (48 + (n & 15)) * 8]);
            dst[0] = (unsigned)ehi | ((unsigned)elo << 16);
            dst[1] = 0u; dst[2] = 0u; dst[3] = 0u;
        }
    }
    __syncthreads();

    float* out0 = out;
    float* out1 = out + B_*C_*HW_;
    float* out2 = out + 2*B_*C_*HW_;

    for (int mt = wave; mt < TILES_PER_BLOCK; mt += 4) {
        const int posT = chunk * (TILES_PER_BLOCK*16) + mt * 16;
        const int bimg = posT >> 12;
        const int hw   = posT & (HW_-1);
        const int ybase = (bimg*C_ + g*D_)*HW_ + hw;     // < 2^23, 32-bit safe
        const float* yb = y + ybase;

        // ---- A: lane (c,q) holds (-2x)[pos=posT+c][k=q*8+j]; trunc/RNE split ----
        s16x8 Ah = {0,0,0,0,0,0,0,0}, Al = {0,0,0,0,0,0,0,0};
        if (q < 3) {
            #pragma unroll
            for (int j = 0; j < 8; ++j) {
                float xv = -2.0f * yb[(q*8+j)*HW_ + c];
                unsigned u = __float_as_uint(xv);
                Ah[j] = (short)(u >> 16);                          // truncation hi
                Al[j] = (short)f2bf(xv - __uint_as_float(u & 0xFFFF0000u));
            }
        } else {
            Ah[0] = (short)0x3F80; Ah[1] = (short)0x3F80;   // 1.0 for e2 dims
        }

        // ---- screen: 32 tiles x 2 MFMA; per-lane top-2 (5-bit tile keys) ----
        unsigned b1[4], b2[4];
        #pragma unroll
        for (int r=0;r<4;++r){ b1[r]=0xFFFFFFFFu; b2[r]=0xFFFFFFFFu; }

        #pragma unroll 8
        for (int t = 0; t < 32; ++t) {
            s16x8 bh = *(const s16x8*)(&sB[t*512 + lane*8]);
            f32x4 acc = {256.0f, 256.0f, 256.0f, 256.0f};
            acc = __builtin_amdgcn_mfma_f32_16x16x32_bf16(Ah, bh, acc, 0,0,0);
            acc = __builtin_amdgcn_mfma_f32_16x16x32_bf16(Al, bh, acc, 0,0,0);
            #pragma unroll
            for (int r=0;r<4;++r){
                unsigned key = (__float_as_uint(acc[r]) & 0xFFFFFFE0u) | (unsigned)t;
                b2[r] = umin_(umax_(b1[r], key), b2[r]);
                b1[r] = umin_(b1[r], key);
            }
        }

        // ---- rebuild 9-bit-code keys (quant 2^-6); butterfly top-3 over 16 cols ----
        unsigned u1[4],u2[4],u3[4];
        #pragma unroll
        for (int r=0;r<4;++r){
            u1[r] = (b1[r] & 0xFFFFFE00u) | (((b1[r]&31u)<<4) | (unsigned)c);
            u2[r] = (b2[r] & 0xFFFFFE00u) | (((b2[r]&31u)<<4) | (unsigned)c);
            u3[r] = 0xFFFFFFFFu;
        }
        #pragma unroll
        for (int d=1; d<16; d<<=1){
            #pragma unroll
            for (int r=0;r<4;++r){
                unsigned o1=__shfl_xor(u1[r],d,64), o2=__shfl_xor(u2[r],d,64), o3=__shfl_xor(u3[r],d,64);
                unsigned x = umax_(u1[r],o1);
                unsigned yv= umin_(u2[r],o2);
                unsigned w = umax_(u2[r],o2);
                unsigned z = umin_(u3[r],o3);
                u1[r]=umin_(u1[r],o1);
                u2[r]=umin_(x,yv);
                u3[r]=umin_(umax_(x,yv), umin_(w,z));
            }
        }

        // ---- fp64 recheck, lane (row=(q<<2)+(c>>2), cand=c&3), 4 indep chains ----
        const int rr = c >> 2, cand = c & 3, row = (q<<2) + rr;
        unsigned s1v = (rr==0)?u1[0]:(rr==1)?u1[1]:(rr==2)?u1[2]:u1[3];
        unsigned s2v = (rr==0)?u2[0]:(rr==1)?u2[1]:(rr==2)?u2[2]:u2[3];
        unsigned s3v = (rr==0)?u3[0]:(rr==1)?u3[1]:(rr==2)?u3[2]:u3[3];
        unsigned sel = (cand==0)?s1v:(cand==1)?s2v:s3v;
        int kc = (int)(sel & 511u);

        const f32x4* ce4 = (const f32x4*)(cbg + kc * D_);
        float ef[24];
        #pragma unroll
        for (int v=0; v<6; ++v) *(f32x4*)&ef[v*4] = ce4[v];
        double a0=0.0, a1=0.0, a2=0.0, a3=0.0;
        #pragma unroll
        for (int j=0;j<24;j+=4){
            double e0=(double)ef[j],   e1=(double)ef[j+1];
            double e2=(double)ef[j+2], e3=(double)ef[j+3];
            double x0=-2.0*(double)yb[j*HW_ + row];
            double x1=-2.0*(double)yb[(j+1)*HW_ + row];
            double x2=-2.0*(double)yb[(j+2)*HW_ + row];
            double x3=-2.0*(double)yb[(j+3)*HW_ + row];
            a0 = fma(e0, e0+x0, a0);
            a1 = fma(e1, e1+x1, a1);   // e*(e+x) == e^2 + x*e? NO -- see below
            a2 = fma(e2, e2+x2, a2);
            a3 = fma(e3, e3+x3, a3);
        }
        // NOTE: e*(e+x) reassociates the *rounding* but both ours and np's fp64
        // noise are ~1e-13 <<< any decidable gap; ordering is preserved.
        double s = ((a0 + a1) + (a2 + a3)) + 256.0;
        u64 key64 = (((u64)__double_as_longlong(s)) & ~0x1FFull) | (u64)kc;
        if (cand == 3) key64 = ~0ull;
        u64 o = __shfl_xor(key64, 1, 64); key64 = o < key64 ? o : key64;
        o = __shfl_xor(key64, 2, 64);     key64 = o < key64 ? o : key64;
        int kwin = (int)(key64 & 511ull);

        // ---- cooperative epilogue: 64 lanes cover 24ch x 16pos x 2 outputs ----
        const int p = c;
        const int srcl = ((p>>2)<<4) | ((p&3)<<2);
        int kw = __shfl(kwin, srcl, 64);
        const float* cw = cbg + kw * D_;
        #pragma unroll
        for (int i=0;i<6;++i){
            int ch = i*4 + q;
            float val = cw[ch];
            int oo = ybase + ch*HW_ + p;
            out0[oo] = val;
            out1[oo] = val;
        }
        if (lane < 16)
            out2[(bimg*G_ + g)*HW_ + hw + lane] = (float)kw;
    }
}

extern "C" void kernel_launch(void* const* d_in, const int* in_sizes, int n_in,
                              void* d_out, int out_size, void* d_ws, size_t ws_size,
                              hipStream_t stream) {
    const float* y  = (const float*)d_in[0];
    const float* cb = (const float*)d_in[1];
    float* out = (float*)d_out;

    const int nblocks = 256 * G_;   // 256 chunks of 128 positions x 8 groups = 2048
    vq_mfma3<<<dim3(nblocks), dim3(THREADS), 0, stream>>>(y, cb, out);
}

// Round 9
// 119.492 us; speedup vs baseline: 1.0277x; 1.0277x over previous
//
#include <hip/hip_runtime.h>

// y: [B=8, C=192, H=64, W=64] f32; codebooks: [G=8, K=512, d=24] f32
// out (f32, concat): universal_ctx | y_ba | code_index [B,1,G,H,W]
#define B_   8
#define C_   192
#define HW_  4096
#define G_   8
#define K_   512
#define D_   24
#define CBSZ (K_ * D_)
#define THREADS 256
#define TILES_PER_BLOCK 16    // 256 positions per block

typedef float  f32x4 __attribute__((ext_vector_type(4)));
typedef int    i32x4 __attribute__((ext_vector_type(4)));
typedef short  s16x8 __attribute__((ext_vector_type(8)));
typedef short  s16x4 __attribute__((ext_vector_type(4)));
typedef unsigned long long u64;

static __device__ __forceinline__ unsigned umin_(unsigned a, unsigned b){return a<b?a:b;}
static __device__ __forceinline__ unsigned umax_(unsigned a, unsigned b){return a>b?a:b;}
static __device__ __forceinline__ unsigned short f2bf(float x){       // RNE f32->bf16
    unsigned u=__float_as_uint(x);
    return (unsigned short)((u + 0x7FFFu + ((u>>16)&1u))>>16);
}
static __device__ __forceinline__ float bf2f(unsigned short h){return __uint_as_float(((unsigned)h)<<16);}

__global__ __launch_bounds__(THREADS, 4) void vq_mfma4(
    const float* __restrict__ y, const float* __restrict__ cb, float* __restrict__ out)
{
    // [tile:32][lane:64][j:8] bf16; lane l=(qq*16+cc): code t*16+cc, k=qq*8+j.
    // qq==3 rows j=0,1 hold e2_hi/e2_lo (k=24,25); rest zero. 32 KiB.
    __shared__ unsigned short sB[32 * 512];

    const int bid = blockIdx.x;
    const int g = bid & 7;
    const int chunk = bid >> 3;
    const int tid = threadIdx.x;
    const int wave = tid >> 6, lane = tid & 63;
    const int c = lane & 15, q = lane >> 4;

    const float* cbg = cb + g * CBSZ;

    // ---- stage codebook hi-bf16 fragments + e2 pair (identical to R7/R8) ----
    {
        const f32x4* cb4 = (const f32x4*)cbg;
        for (int i = tid; i < CBSZ/4; i += THREADS) {
            f32x4 v = cb4[i];
            int i4 = i << 2;
            int n  = i4 / 24;          // float4 never crosses a row (24%4==0)
            int k0 = i4 - n * 24;
            int off = (n >> 4) * 512 + (((k0 >> 3) << 4) + (n & 15)) * 8 + (k0 & 7);
            s16x4 h;
            h[0]=(short)f2bf(v[0]); h[1]=(short)f2bf(v[1]);
            h[2]=(short)f2bf(v[2]); h[3]=(short)f2bf(v[3]);
            *(s16x4*)(&sB[off]) = h;
        }
        for (int n = tid; n < K_; n += THREADS) {
            const float* row = cbg + n * D_;
            double s0 = 0.0, s1 = 0.0;
            #pragma unroll
            for (int j = 0; j < D_; j += 2) {
                double v0 = (double)row[j], v1 = (double)row[j+1];
                s0 = fma(v0,v0,s0); s1 = fma(v1,v1,s1);
            }
            double s = s0 + s1;
            unsigned short ehi = f2bf((float)s);
            unsigned short elo = f2bf((float)(s - (double)bf2f(ehi)));
            unsigned* dst = (unsigned*)(&sB[(n >> 4) * 512 + (48 + (n & 15)) * 8]);
            dst[0] = (unsigned)ehi | ((unsigned)elo << 16);
            dst[1] = 0u; dst[2] = 0u; dst[3] = 0u;
        }
    }
    __syncthreads();

    float* out0 = out;
    float* out1 = out + B_*C_*HW_;
    float* out2 = out + 2*B_*C_*HW_;

    for (int mt = wave; mt < TILES_PER_BLOCK; mt += 4) {
        const int posT = chunk * (TILES_PER_BLOCK*16) + mt * 16;
        const int bimg = posT >> 12;
        const int hw   = posT & (HW_-1);
        const int ybase = (bimg*C_ + g*D_)*HW_ + hw;
        const float* yb = y + ybase;

        // ---- B operand (positions): lane (c,q) holds (-2x)[pos c][k=q*8+j].
        //      q==3: k=24,25 = 1.0 (pairs with e2 rows of A). Keep xf for recheck. ----
        float xf[8];
        unsigned hx[4], lx[4];
        if (q < 3) {
            const float* yq = yb + (q*8)*HW_ + c;
            #pragma unroll
            for (int jj = 0; jj < 8; ++jj) xf[jj] = -2.0f * yq[jj*HW_];
            #pragma unroll
            for (int p2 = 0; p2 < 4; ++p2) {
                float f0 = xf[2*p2], f1 = xf[2*p2+1];
                unsigned u0 = __float_as_uint(f0), u1v = __float_as_uint(f1);
                hx[p2] = (u1v & 0xFFFF0000u) | (u0 >> 16);        // trunc-hi pair
                float l0 = f0 - __uint_as_float(u0 & 0xFFFF0000u);
                float l1 = f1 - __uint_as_float(u1v & 0xFFFF0000u);
                lx[p2] = (unsigned)f2bf(l0) | ((unsigned)f2bf(l1) << 16);
            }
        } else {
            #pragma unroll
            for (int jj = 0; jj < 8; ++jj) xf[jj] = 0.0f;
            hx[0] = 0x3F803F80u; hx[1]=0u; hx[2]=0u; hx[3]=0u;
            lx[0]=0u; lx[1]=0u; lx[2]=0u; lx[3]=0u;
        }
        const s16x8 Xh = __builtin_bit_cast(s16x8, (i32x4){(int)hx[0],(int)hx[1],(int)hx[2],(int)hx[3]});
        const s16x8 Xl = __builtin_bit_cast(s16x8, (i32x4){(int)lx[0],(int)lx[1],(int)lx[2],(int)lx[3]});

        // ---- screen: A=codes (LDS frag), B=x. D[row=q*4+r]=code, D[col=c]=pos.
        //      Each lane: top-3 over its 128 codes (quant 2^-6, 9-bit code id). ----
        unsigned b1=0xFFFFFFFFu, b2=0xFFFFFFFFu, b3=0xFFFFFFFFu;
        const unsigned qr4 = (unsigned)(q << 2);
        #pragma unroll 8
        for (int t = 0; t < 32; ++t) {
            s16x8 eh = *(const s16x8*)(&sB[t*512 + lane*8]);
            f32x4 acc = {256.0f, 256.0f, 256.0f, 256.0f};
            acc = __builtin_amdgcn_mfma_f32_16x16x32_bf16(eh, Xh, acc, 0,0,0);
            acc = __builtin_amdgcn_mfma_f32_16x16x32_bf16(eh, Xl, acc, 0,0,0);
            const unsigned cbase = ((unsigned)t << 4) + qr4;
            #pragma unroll
            for (int r = 0; r < 4; ++r) {
                unsigned key = (__float_as_uint(acc[r]) & 0xFFFFFE00u) + (cbase + r);
                b3 = umin_(umax_(b2, key), b3);     // uses pre-update b2
                b2 = umin_(umax_(b1, key), b2);     // uses pre-update b1
                b1 = umin_(b1, key);
            }
        }

        // ---- 2-step butterfly (xor 16, 32): global top-3 for pos c, all lanes ----
        #pragma unroll
        for (int d = 16; d < 64; d <<= 1) {
            unsigned o1=__shfl_xor(b1,d,64), o2=__shfl_xor(b2,d,64), o3=__shfl_xor(b3,d,64);
            unsigned x = umax_(b1,o1);
            unsigned yv= umin_(b2,o2);
            unsigned w = umax_(b2,o2);
            unsigned z = umin_(b3,o3);
            b1 = umin_(b1,o1);
            b2 = umin_(x,yv);
            b3 = umin_(umax_(x,yv), umin_(w,z));
        }

        // ---- gap-gated exact fp64 recheck (partials from registers, no y reload) ----
        const float v1 = __uint_as_float(b1 & 0xFFFFFE00u);
        const float v2 = __uint_as_float(b2 & 0xFFFFFE00u);
        int kwin;
        if (__ballot((v2 - v1) < 0.20f) == 0ull) {
            kwin = (int)(b1 & 511u);        // unambiguous everywhere in this wave
        } else {
            double xd[8];
            #pragma unroll
            for (int jj = 0; jj < 8; ++jj) xd[jj] = (double)xf[jj];
            const unsigned cands[3] = {b1, b2, b3};
            u64 bestk = ~0ull;
            #pragma unroll
            for (int ci = 0; ci < 3; ++ci) {
                int kc = (int)(cands[ci] & 511u);
                double s = 0.0;
                if (q < 3) {
                    const f32x4* ce4 = (const f32x4*)(cbg + kc*D_ + (q<<3));
                    float ef[8];
                    *(f32x4*)&ef[0] = ce4[0];
                    *(f32x4*)&ef[4] = ce4[1];
                    #pragma unroll
                    for (int jj = 0; jj < 8; ++jj) {
                        double ev = (double)ef[jj];
                        s = fma(ev, ev, s);          // e^2
                        s = fma(xd[jj], ev, s);      // -2 x.e
                    }
                }
                s += __shfl_xor(s, 16, 64);          // sum q-partials (q=3 adds 0)
                s += __shfl_xor(s, 32, 64);
                s += 256.0;
                u64 kk = (((u64)__double_as_longlong(s)) & ~0x1FFull) | (u64)kc;
                bestk = kk < bestk ? kk : bestk;
            }
            kwin = (int)(bestk & 511ull);
        }

        // ---- epilogue: lane (c,q<3) writes dims q*8..q*8+7 of pos c, both outputs ----
        const float* cw = cbg + kwin * D_;
        if (q < 3) {
            const f32x4* cw4 = (const f32x4*)(cw + (q<<3));
            float v[8];
            *(f32x4*)&v[0] = cw4[0];
            *(f32x4*)&v[4] = cw4[1];
            const int ob = ybase + (q*8)*HW_ + c;
            #pragma unroll
            for (int jj = 0; jj < 8; ++jj) {
                out0[ob + jj*HW_] = v[jj];
                out1[ob + jj*HW_] = v[jj];
            }
        }
        if (lane < 16)
            out2[(bimg*G_ + g)*HW_ + hw + lane] = (float)kwin;
    }
}

extern "C" void kernel_launch(void* const* d_in, const int* in_sizes, int n_in,
                              void* d_out, int out_size, void* d_ws, size_t ws_size,
                              hipStream_t stream) {
    const float* y  = (const float*)d_in[0];
    const float* cb = (const float*)d_in[1];
    float* out = (float*)d_out;

    const int nblocks = 128 * G_;   // 128 chunks of 256 positions x 8 groups = 1024
    vq_mfma4<<<dim3(nblocks), dim3(THREADS), 0, stream>>>(y, cb, out);
}

// Round 10
// 117.700 us; speedup vs baseline: 1.0434x; 1.0152x over previous
//
#include <hip/hip_runtime.h>

// y: [B=8, C=192, H=64, W=64] f32; codebooks: [G=8, K=512, d=24] f32
// out (f32, concat): universal_ctx | y_ba | code_index [B,1,G,H,W]
// d_ws: >= 256 KiB scratch; holds 8 precomputed 32 KiB codebook fragment images.
#define B_   8
#define C_   192
#define HW_  4096
#define G_   8
#define K_   512
#define D_   24
#define CBSZ (K_ * D_)
#define THREADS 256
#define TILES_PER_BLOCK 8     // 128 positions per block

typedef float  f32x4 __attribute__((ext_vector_type(4)));
typedef int    i32x4 __attribute__((ext_vector_type(4)));
typedef short  s16x8 __attribute__((ext_vector_type(8)));
typedef short  s16x4 __attribute__((ext_vector_type(4)));
typedef unsigned long long u64;

static __device__ __forceinline__ unsigned umin_(unsigned a, unsigned b){return a<b?a:b;}
static __device__ __forceinline__ unsigned umax_(unsigned a, unsigned b){return a>b?a:b;}
static __device__ __forceinline__ unsigned short f2bf(float x){       // RNE f32->bf16
    unsigned u=__float_as_uint(x);
    return (unsigned short)((u + 0x7FFFu + ((u>>16)&1u))>>16);
}
static __device__ __forceinline__ float bf2f(unsigned short h){return __uint_as_float(((unsigned)h)<<16);}

// ---------- pre-kernel: build per-group 32 KiB fragment images in ws ----------
// Image layout (halfwords), per group: idx = t*512 + lane*8 + j, where
// lane = qq*16 + cc encodes code n = t*16+cc, k = qq*8+j (qq<3 = e_hi bf16);
// lanes 48..63: j=0,1 = e2_hi/e2_lo bf16 pair (k=24,25), j>=2 zero.
__global__ __launch_bounds__(THREADS) void vq_stage(
    const float* __restrict__ cb, unsigned short* __restrict__ ws)
{
    const int g = blockIdx.x >> 3;
    const int s = blockIdx.x & 7;              // 64-code slice of this group
    const int tid = threadIdx.x;
    const float* cbg = cb + g * CBSZ;
    unsigned short* img = ws + g * 16384;      // 32 KiB per group

    // fragment part: this slice covers float4 indices [s*384, s*384+384)
    for (int i = tid; i < 384; i += THREADS) {
        int gi = s * 384 + i;
        f32x4 v = ((const f32x4*)cbg)[gi];
        int i4 = gi << 2;
        int n  = i4 / 24;                      // float4 never crosses a row
        int k0 = i4 - n * 24;
        int off = (n >> 4) * 512 + (((k0 >> 3) << 4) + (n & 15)) * 8 + (k0 & 7);
        s16x4 h;
        h[0]=(short)f2bf(v[0]); h[1]=(short)f2bf(v[1]);
        h[2]=(short)f2bf(v[2]); h[3]=(short)f2bf(v[3]);
        *(s16x4*)(&img[off]) = h;              // 8B-aligned (k0&7 in {0,4})
    }
    // e2 pairs for the 64 codes of this slice
    if (tid < 64) {
        int n = s * 64 + tid;
        const float* row = cbg + n * D_;
        double s0 = 0.0, s1 = 0.0;
        #pragma unroll
        for (int j = 0; j < D_; j += 2) {
            double v0 = (double)row[j], v1 = (double)row[j+1];
            s0 = fma(v0,v0,s0); s1 = fma(v1,v1,s1);
        }
        double sv = s0 + s1;
        unsigned short ehi = f2bf((float)sv);
        unsigned short elo = f2bf((float)(sv - (double)bf2f(ehi)));
        i32x4 pack = { (int)((unsigned)ehi | ((unsigned)elo << 16)), 0, 0, 0 };
        *(i32x4*)(&img[(n >> 4) * 512 + (48 + (n & 15)) * 8]) = pack;  // 16B-aligned
    }
}

// ------------------------------- main kernel ---------------------------------
__global__ __launch_bounds__(THREADS, 5) void vq_mfma5(
    const float* __restrict__ y, const float* __restrict__ cb,
    const unsigned short* __restrict__ ws, float* __restrict__ out)
{
    __shared__ unsigned short sB[32 * 512];    // 32 KiB -> 5 blocks/CU resident

    const int bid = blockIdx.x;
    const int g = bid & 7;
    const int chunk = bid >> 3;
    const int tid = threadIdx.x;
    const int wave = tid >> 6, lane = tid & 63;
    const int c = lane & 15, q = lane >> 4;

    const float* cbg = cb + g * CBSZ;

    // ---- staging = straight 32 KiB copy of the precomputed image ----
    {
        const char* src = (const char*)(ws + g * 16384);
        char* dst = (char*)sB;
        #pragma unroll
        for (int it = 0; it < 8; ++it)
            *(i32x4*)(dst + it*4096 + tid*16) = *(const i32x4*)(src + it*4096 + tid*16);
    }
    __syncthreads();

    float* out0 = out;
    float* out1 = out + B_*C_*HW_;
    float* out2 = out + 2*B_*C_*HW_;

    for (int mt = wave; mt < TILES_PER_BLOCK; mt += 4) {
        const int posT = chunk * (TILES_PER_BLOCK*16) + mt * 16;
        const int bimg = posT >> 12;
        const int hw   = posT & (HW_-1);
        const int ybase = (bimg*C_ + g*D_)*HW_ + hw;
        const float* yb = y + ybase;

        // ---- B operand: lane (c,q) holds (-2x)[pos c][k=q*8+j]; q==3 -> 1.0 pair ----
        float xf[8];
        unsigned hx[4], lx[4];
        if (q < 3) {
            const float* yq = yb + (q*8)*HW_ + c;
            #pragma unroll
            for (int jj = 0; jj < 8; ++jj) xf[jj] = -2.0f * yq[jj*HW_];
            #pragma unroll
            for (int p2 = 0; p2 < 4; ++p2) {
                float f0 = xf[2*p2], f1 = xf[2*p2+1];
                unsigned u0 = __float_as_uint(f0), u1v = __float_as_uint(f1);
                hx[p2] = (u1v & 0xFFFF0000u) | (u0 >> 16);        // trunc-hi pair
                float l0 = f0 - __uint_as_float(u0 & 0xFFFF0000u);
                float l1 = f1 - __uint_as_float(u1v & 0xFFFF0000u);
                lx[p2] = (unsigned)f2bf(l0) | ((unsigned)f2bf(l1) << 16);
            }
        } else {
            #pragma unroll
            for (int jj = 0; jj < 8; ++jj) xf[jj] = 0.0f;
            hx[0] = 0x3F803F80u; hx[1]=0u; hx[2]=0u; hx[3]=0u;
            lx[0]=0u; lx[1]=0u; lx[2]=0u; lx[3]=0u;
        }
        const s16x8 Xh = __builtin_bit_cast(s16x8, (i32x4){(int)hx[0],(int)hx[1],(int)hx[2],(int)hx[3]});
        const s16x8 Xl = __builtin_bit_cast(s16x8, (i32x4){(int)lx[0],(int)lx[1],(int)lx[2],(int)lx[3]});

        // ---- screen: A=codes (LDS frags), B=x; lane owns pos c, 128 codes.
        //      Per-lane top-3 (quant 2^-6, 9-bit code id). ----
        unsigned b1=0xFFFFFFFFu, b2=0xFFFFFFFFu, b3=0xFFFFFFFFu;
        const unsigned qr4 = (unsigned)(q << 2);
        #pragma unroll 8
        for (int t = 0; t < 32; ++t) {
            s16x8 eh = *(const s16x8*)(&sB[t*512 + lane*8]);
            f32x4 acc = {256.0f, 256.0f, 256.0f, 256.0f};
            acc = __builtin_amdgcn_mfma_f32_16x16x32_bf16(eh, Xh, acc, 0,0,0);
            acc = __builtin_amdgcn_mfma_f32_16x16x32_bf16(eh, Xl, acc, 0,0,0);
            const unsigned cbase = ((unsigned)t << 4) + qr4;
            #pragma unroll
            for (int r = 0; r < 4; ++r) {
                unsigned key = (__float_as_uint(acc[r]) & 0xFFFFFE00u) + (cbase + r);
                b3 = umin_(umax_(b2, key), b3);
                b2 = umin_(umax_(b1, key), b2);
                b1 = umin_(b1, key);
            }
        }

        // ---- 2-step butterfly (xor 16, 32): global top-3 for pos c ----
        #pragma unroll
        for (int d = 16; d < 64; d <<= 1) {
            unsigned o1=__shfl_xor(b1,d,64), o2=__shfl_xor(b2,d,64), o3=__shfl_xor(b3,d,64);
            unsigned x = umax_(b1,o1);
            unsigned yv= umin_(b2,o2);
            unsigned w = umax_(b2,o2);
            unsigned z = umin_(b3,o3);
            b1 = umin_(b1,o1);
            b2 = umin_(x,yv);
            b3 = umin_(umax_(x,yv), umin_(w,z));
        }

        // ---- gap-gated exact fp64 recheck (register partials, no y reload) ----
        const float v1 = __uint_as_float(b1 & 0xFFFFFE00u);
        const float v2 = __uint_as_float(b2 & 0xFFFFFE00u);
        int kwin;
        if (__ballot((v2 - v1) < 0.20f) == 0ull) {
            kwin = (int)(b1 & 511u);
        } else {
            double xd[8];
            #pragma unroll
            for (int jj = 0; jj < 8; ++jj) xd[jj] = (double)xf[jj];
            const unsigned cands[3] = {b1, b2, b3};
            u64 bestk = ~0ull;
            #pragma unroll
            for (int ci = 0; ci < 3; ++ci) {
                int kc = (int)(cands[ci] & 511u);
                double s = 0.0;
                if (q < 3) {
                    const f32x4* ce4 = (const f32x4*)(cbg + kc*D_ + (q<<3));
                    float ef[8];
                    *(f32x4*)&ef[0] = ce4[0];
                    *(f32x4*)&ef[4] = ce4[1];
                    #pragma unroll
                    for (int jj = 0; jj < 8; ++jj) {
                        double ev = (double)ef[jj];
                        s = fma(ev, ev, s);
                        s = fma(xd[jj], ev, s);
                    }
                }
                s += __shfl_xor(s, 16, 64);
                s += __shfl_xor(s, 32, 64);
                s += 256.0;
                u64 kk = (((u64)__double_as_longlong(s)) & ~0x1FFull) | (u64)kc;
                bestk = kk < bestk ? kk : bestk;
            }
            kwin = (int)(bestk & 511ull);
        }

        // ---- epilogue: lane (c,q<3) writes dims q*8..q*8+7 of pos c ----
        const float* cw = cbg + kwin * D_;
        if (q < 3) {
            const f32x4* cw4 = (const f32x4*)(cw + (q<<3));
            float v[8];
            *(f32x4*)&v[0] = cw4[0];
            *(f32x4*)&v[4] = cw4[1];
            const int ob = ybase + (q*8)*HW_ + c;
            #pragma unroll
            for (int jj = 0; jj < 8; ++jj) {
                out0[ob + jj*HW_] = v[jj];
                out1[ob + jj*HW_] = v[jj];
            }
        }
        if (lane < 16)
            out2[(bimg*G_ + g)*HW_ + hw + lane] = (float)kwin;
    }
}

extern "C" void kernel_launch(void* const* d_in, const int* in_sizes, int n_in,
                              void* d_out, int out_size, void* d_ws, size_t ws_size,
                              hipStream_t stream) {
    const float* y  = (const float*)d_in[0];
    const float* cb = (const float*)d_in[1];
    float* out = (float*)d_out;
    unsigned short* ws = (unsigned short*)d_ws;   // needs 256 KiB

    vq_stage<<<dim3(64), dim3(THREADS), 0, stream>>>(cb, ws);
    const int nblocks = 256 * G_;                 // 256 chunks x 8 groups = 2048
    vq_mfma5<<<dim3(nblocks), dim3(THREADS), 0, stream>>>(y, cb, ws, out);
}